// Round 3
// baseline (59.703 us; speedup 1.0000x reference)
//
#include <hip/hip_runtime.h>

// Sliding-window variance, window W=64 looking forward, clipped at row end.
// x: (B=32, L=16384) fp32 row-major; out: (B, L) fp32.
// var[b,i] = Var(x[b, i : min(i+W, L)])   (population variance, divide by n)
//
// One-pass var = E[x^2] - mean^2 (threshold headroom 8x, verified R1).
// Per-block: stage 1024 outputs + 64 halo in LDS (coalesced float4),
// per-thread: 4 outputs via tree-reduced first window + sliding updates.

constexpr int W      = 64;
constexpr int K      = 4;                 // outputs per thread
constexpr int T      = 256;               // threads per block
constexpr int CHUNK  = T * K;             // 1024 outputs per block
constexpr int LDS_F4 = (CHUNK + W) / 4;   // 272 float4 = 1088 floats

__global__ __launch_bounds__(T) void sliding_var64_kernel(
    const float* __restrict__ x, float* __restrict__ out,
    int L, int chunksPerRow)
{
    __shared__ float4 lds4[LDS_F4];
    float* lds = reinterpret_cast<float*>(lds4);

    const int row = blockIdx.x / chunksPerRow;
    const int c0  = (blockIdx.x % chunksPerRow) * CHUNK;
    const float* xr   = x   + (size_t)row * L;
    float*       outr = out + (size_t)row * L;
    const int tid = threadIdx.x;

    // ---- stage CHUNK + W floats into LDS, coalesced float4 loads ----
    const float4* src4 = reinterpret_cast<const float4*>(xr + c0);
    for (int i = tid; i < LDS_F4; i += T) {
        const int g4 = c0 + 4 * i;
        float4 v;
        if (g4 + 3 < L) {
            v = src4[i];
        } else {                             // row-end halo: pad with zeros
            v.x = (g4 + 0 < L) ? xr[g4 + 0] : 0.0f;
            v.y = (g4 + 1 < L) ? xr[g4 + 1] : 0.0f;
            v.z = (g4 + 2 < L) ? xr[g4 + 2] : 0.0f;
            v.w = (g4 + 3 < L) ? xr[g4 + 3] : 0.0f;
        }
        lds4[i] = v;
    }
    __syncthreads();

    // ---- pull this thread's 68-float span into registers, with per-group
    //      partial sums (tree reduction: dep depth ~6 instead of 64) ----
    float wr[68];
    float gs[16], gq[16];
    #pragma unroll
    for (int jj = 0; jj < 17; ++jj) {
        const float4 v = lds4[tid + jj];
        wr[4 * jj + 0] = v.x;
        wr[4 * jj + 1] = v.y;
        wr[4 * jj + 2] = v.z;
        wr[4 * jj + 3] = v.w;
        if (jj < 16) {
            gs[jj] = (v.x + v.y) + (v.z + v.w);
            gq[jj] = (v.x * v.x + v.y * v.y) + (v.z * v.z + v.w * v.w);
        }
    }
    float s = ((((gs[0]  + gs[1])  + (gs[2]  + gs[3]))  +
                ((gs[4]  + gs[5])  + (gs[6]  + gs[7])))  +
               (((gs[8]  + gs[9])  + (gs[10] + gs[11])) +
                ((gs[12] + gs[13]) + (gs[14] + gs[15]))));
    float q = ((((gq[0]  + gq[1])  + (gq[2]  + gq[3]))  +
                ((gq[4]  + gq[5])  + (gq[6]  + gq[7])))  +
               (((gq[8]  + gq[9])  + (gq[10] + gq[11])) +
                ((gq[12] + gq[13]) + (gq[14] + gq[15]))));

    const int base = tid * K;
    float4 res;
    float* resf = reinterpret_cast<float*>(&res);

    #pragma unroll
    for (int k = 0; k < K; ++k) {
        const int g = c0 + base + k;         // global output index
        const int n = L - g;                 // valid elements in window
        float var;
        if (n >= W) {
            const float mean = s * (1.0f / W);
            var = fmaxf(fmaf(-mean, mean, q * (1.0f / W)), 0.0f);
        } else {
            // rare tail (last 63 positions of a row): recompute from LDS
            float ss = 0.0f, qq = 0.0f;
            for (int j = 0; j < n; ++j) {
                const float v = lds[base + k + j];
                ss += v;
                qq = fmaf(v, v, qq);
            }
            const float mean = ss / n;
            var = fmaxf(fmaf(-mean, mean, qq / n), 0.0f);
        }
        resf[k] = var;
        if (k < K - 1) {                     // slide window by one
            const float a = wr[k + W], b = wr[k];
            s += a - b;
            q += fmaf(a, a, -(b * b));
        }
    }

    *reinterpret_cast<float4*>(outr + c0 + base) = res;
}

extern "C" void kernel_launch(void* const* d_in, const int* in_sizes, int n_in,
                              void* d_out, int out_size, void* d_ws, size_t ws_size,
                              hipStream_t stream)
{
    const float* x = (const float*)d_in[0];
    float* out = (float*)d_out;

    const int L = 16384;                  // from setup_inputs
    const int B = out_size / L;           // 32
    const int chunksPerRow = L / CHUNK;   // 16

    dim3 grid(B * chunksPerRow), block(T);
    hipLaunchKernelGGL(sliding_var64_kernel, grid, block, 0, stream,
                       x, out, L, chunksPerRow);
}